// Round 11
// baseline (86.878 us; speedup 1.0000x reference)
//
#include <hip/hip_runtime.h>
#include <math.h>

// DistanceLoss — y_pred (8,2,512,512) f32, y_true (8,2,512,512) f32 -> scalar f32.
// loss = mean[(1 + EDT(y_true)/511) * (softmax(y_pred,C=2) - y_true)^2]
// Three dispatches, no device-scope atomics (round-9 lesson: agent-scope
// release/acquire per block = L2 maintenance storm on multi-XCD gfx950).
// Round-11: cols kernel processes BOTH channels per n (yp read once) and
// reconstructs y_true from d1sq==0 (yt read eliminated).

#define H 512
#define W 512
#define NIMG 16
#define HW (H * W)
#define RW 5                       // exact window radius; certified + fallback
#define SEG 16                     // output rows per thread (cols kernel)
#define HALO (SEG + 2 * RW)        // 26 halo rows
#define JT 256                     // columns per block
#define NBLK (8 * (H / SEG) * (W / JT))   // 512 blocks (per-n, both channels)

static __device__ __forceinline__ float fast_exp2(float x) {
#if __has_builtin(__builtin_amdgcn_exp2f)
    return __builtin_amdgcn_exp2f(x);
#else
    return exp2f(x);
#endif
}
static __device__ __forceinline__ float fast_rcp(float x) {
#if __has_builtin(__builtin_amdgcn_rcpf)
    return __builtin_amdgcn_rcpf(x);
#else
    return 1.0f / x;
#endif
}

// ---------------------------------------------------------------------------
// Pass 1 (validated, absmax 0.0 six times): per-row 1D width-distance squared.
// One wave per row, 8 contiguous elements per lane.
// ---------------------------------------------------------------------------
__global__ __launch_bounds__(256) void edt_rows_kernel(const float* __restrict__ yt,
                                                       float* __restrict__ d1sq) {
    int wid = blockIdx.x * 4 + (threadIdx.x >> 6);
    int lane = threadIdx.x & 63;
    int img = wid >> 9;
    int row = wid & (H - 1);

    const float* rp = yt + ((size_t)img * H + row) * W;
    int k0 = lane * 8;
    float4 va = *reinterpret_cast<const float4*>(rp + k0);
    float4 vb = *reinterpret_cast<const float4*>(rp + k0 + 4);
    float g[8] = { va.x, va.y, va.z, va.w, vb.x, vb.y, vb.z, vb.w };
    const float INF = 1024.0f;
    #pragma unroll
    for (int t = 0; t < 8; ++t) g[t] = (g[t] > 0.5f) ? 0.0f : INF;

    const float BIG = 3.0e38f;
    float pm[8], sm[8];

    float run = BIG;
    #pragma unroll
    for (int t = 0; t < 8; ++t) {
        run = fminf(run, g[t] - (float)(k0 + t));
        pm[t] = run;
    }
    float incl = run;
    #pragma unroll
    for (int d = 1; d < 64; d <<= 1) {
        float o = __shfl_up(incl, d);
        if (lane >= d) incl = fminf(incl, o);
    }
    float excl = __shfl_up(incl, 1);
    if (lane == 0) excl = BIG;

    run = BIG;
    #pragma unroll
    for (int t = 7; t >= 0; --t) {
        run = fminf(run, g[t] + (float)(k0 + t));
        sm[t] = run;
    }
    float incl2 = run;
    #pragma unroll
    for (int d = 1; d < 64; d <<= 1) {
        float o = __shfl_down(incl2, d);
        if (lane < 64 - d) incl2 = fminf(incl2, o);
    }
    float excl2 = __shfl_down(incl2, 1);
    if (lane == 63) excl2 = BIG;

    float out[8];
    #pragma unroll
    for (int t = 0; t < 8; ++t) {
        float kf = (float)(k0 + t);
        float f = kf + fminf(excl, pm[t]);
        float b = -kf + fminf(excl2, sm[t]);
        float d = fminf(f, b);
        out[t] = d * d;              // exact integer in fp32
    }
    float* op = d1sq + (size_t)img * HW + (size_t)row * W + k0;
    *reinterpret_cast<float4*>(op)     = make_float4(out[0], out[1], out[2], out[3]);
    *reinterpret_cast<float4*>(op + 4) = make_float4(out[4], out[5], out[6], out[7]);
}

// ---------------------------------------------------------------------------
// Pass 2: both channels of one n per block. LDS-free windowed exact column
// envelope + fused loss. Window offsets are compile-time constants, paired
// symmetrically: min(w[-k],w[+k]) + k^2. Certification: window min <= 36
// guarantees global optimality; else exact full-column fallback (dead here).
// y_true reconstructed exactly from d1sq: yt==1 <=> d1sq==0 (saves the read).
// Epilogue per channel: p = sigmoid(x_c - x_o) via 1 v_exp_f32 + 1 v_rcp_f32
// (identical sequence to the absmax-0.0-validated rounds 9/10).
// Per-block partial via PLAIN store; visibility via kernel boundary.
// ---------------------------------------------------------------------------
__global__ __launch_bounds__(256) void edt_cols_loss_kernel(
        const float* __restrict__ yp, const float* __restrict__ d1sq,
        double* __restrict__ part) {
    __shared__ double wsum[4];

    const int tid  = threadIdx.x;
    const int lane = tid & 63;
    const int wv   = tid >> 6;
    const int j    = blockIdx.x * JT + tid;
    const int i0   = blockIdx.y * SEG;
    const int n    = blockIdx.z;                 // 0..7
    const int bid  = (blockIdx.z * gridDim.y + blockIdx.y) * gridDim.x + blockIdx.x;

    const float BIG = 3.0e38f;
    const float* dp0 = d1sq + (size_t)(2 * n)     * HW;
    const float* dp1 = d1sq + (size_t)(2 * n + 1) * HW;

    float w0[HALO], w1[HALO];
    #pragma unroll
    for (int k = 0; k < HALO; ++k) {
        int ip = i0 - RW + k;
        bool inb = (ip >= 0 && ip < H);
        int off = ip * W + j;
        w0[k] = inb ? dp0[off] : BIG;
        w1[k] = inb ? dp1[off] : BIG;
    }

    float mn0[SEG], mn1[SEG];
    #pragma unroll
    for (int m = 0; m < SEG; ++m) {
        float a1 = fminf(w0[m + 4], w0[m + 6]) + 1.0f;
        float a2 = fminf(w0[m + 3], w0[m + 7]) + 4.0f;
        float a3 = fminf(w0[m + 2], w0[m + 8]) + 9.0f;
        float a4 = fminf(w0[m + 1], w0[m + 9]) + 16.0f;
        float a5 = fminf(w0[m + 0], w0[m + 10]) + 25.0f;
        mn0[m] = fminf(fminf(fminf(w0[m + 5], a1), fminf(a2, a3)), fminf(a4, a5));
        float b1 = fminf(w1[m + 4], w1[m + 6]) + 1.0f;
        float b2 = fminf(w1[m + 3], w1[m + 7]) + 4.0f;
        float b3 = fminf(w1[m + 2], w1[m + 8]) + 9.0f;
        float b4 = fminf(w1[m + 1], w1[m + 9]) + 16.0f;
        float b5 = fminf(w1[m + 0], w1[m + 10]) + 25.0f;
        mn1[m] = fminf(fminf(fminf(w1[m + 5], b1), fminf(b2, b3)), fminf(b4, b5));
    }

    bool need = false;
    #pragma unroll
    for (int m = 0; m < SEG; ++m) need |= (mn0[m] > 36.0f) | (mn1[m] > 36.0f);
    if (__any(need)) {          // exact fallback — provably dead for this input
        for (int ip = 0; ip < H; ++ip) {
            float v0 = dp0[ip * W + j];
            float v1 = dp1[ip * W + j];
            #pragma unroll
            for (int m = 0; m < SEG; ++m) {
                int d = (i0 + m) - ip;
                float dd = (float)(d * d);
                mn0[m] = fminf(mn0[m], v0 + dd);
                mn1[m] = fminf(mn1[m], v1 + dd);
            }
        }
    }

    // ---- fused loss epilogue, both channels ----
    const float* x0p = yp + (size_t)(2 * n)     * HW;
    const float* x1p = yp + (size_t)(2 * n + 1) * HW;
    const float LOG2E = 1.44269504088896340736f;

    double local = 0.0;
    #pragma unroll
    for (int m = 0; m < SEG; ++m) {
        int idx = (i0 + m) * W + j;
        float x0 = x0p[idx], x1 = x1p[idx];
        // channel 0: p0 = sigmoid(x0 - x1)
        float e01 = fast_exp2((x1 - x0) * LOG2E);
        float p0  = fast_rcp(1.0f + e01);
        // channel 1: p1 = sigmoid(x1 - x0)
        float e10 = fast_exp2((x0 - x1) * LOG2E);
        float p1  = fast_rcp(1.0f + e10);
        float yt0 = (w0[m + RW] == 0.0f) ? 1.0f : 0.0f;   // exact: d1sq==0 <=> yt==1
        float yt1 = (w1[m + RW] == 0.0f) ? 1.0f : 0.0f;
        float dm0 = sqrtf(mn0[m]) * (1.0f / 511.0f);
        float dm1 = sqrtf(mn1[m]) * (1.0f / 511.0f);
        float df0 = p0 - yt0;
        float df1 = p1 - yt1;
        local += (double)((1.0f + dm0) * (df0 * df0))
               + (double)((1.0f + dm1) * (df1 * df1));
    }

    #pragma unroll
    for (int d = 32; d > 0; d >>= 1) local += __shfl_down(local, d);
    if (lane == 0) wsum[wv] = local;
    __syncthreads();
    if (tid == 0)
        part[bid] = wsum[0] + wsum[1] + wsum[2] + wsum[3];   // plain store
}

// Sum the 512 per-block partials and normalize.
__global__ __launch_bounds__(256) void finalize_kernel(const double* __restrict__ part,
                                                       float* __restrict__ out) {
    __shared__ double ws[4];
    int t = threadIdx.x;
    double v = part[t] + part[t + 256];
    #pragma unroll
    for (int d = 32; d > 0; d >>= 1) v += __shfl_down(v, d);
    if ((t & 63) == 0) ws[t >> 6] = v;
    __syncthreads();
    if (t == 0)
        out[0] = (float)((ws[0] + ws[1] + ws[2] + ws[3]) / (double)(NIMG * HW));
}

extern "C" void kernel_launch(void* const* d_in, const int* in_sizes, int n_in,
                              void* d_out, int out_size, void* d_ws, size_t ws_size,
                              hipStream_t stream) {
    const float* y_pred = (const float*)d_in[0];
    const float* y_true = (const float*)d_in[1];
    float* out = (float*)d_out;

    double* part = (double*)d_ws;                       // 512 doubles
    float*  d1sq = (float*)((char*)d_ws + 16384);       // 16.8 MB

    edt_rows_kernel<<<dim3(NIMG * H / 4), 256, 0, stream>>>(y_true, d1sq);
    edt_cols_loss_kernel<<<dim3(W / JT, H / SEG, 8), 256, 0, stream>>>(
        y_pred, d1sq, part);
    finalize_kernel<<<1, 256, 0, stream>>>(part, out);
}